// Round 3
// baseline (230.876 us; speedup 1.0000x reference)
//
#include <hip/hip_runtime.h>

// ---------------------------------------------------------------------------
// CirculantLinear via length-4 rfft + 3-mult complex product (Karatsuba):
//   bins: k=0 real (O0), k=1 complex (Or,Oi), k=2 real (O2)
//   K1=(Xr+Xi)·Er, K2=Xr·(Ei-Er), K3=Xi·(Ei+Er);  Or=K1-K3, Oi=K1+K2
// -> 5 uniform bf16 GEMMs, each M=4096 N=1024 K=1024 (42.9 GFLOP total),
//    1280 identical blocks = exactly 5 blocks/CU -> no tail imbalance.
//
// Primary ws layout (needs 66 MiB):
//   [0,40MiB)  Xp bf16 4096x5120: cols [X0|Xr|Xi|Xr+Xi|X2]
//   [40,50MiB) Bp bf16 5 segs of 1024x1024: [E0|Er|Ei-Er|Ei+Er|E2]
//   [50,66MiB) K3 fp32 4096x1024
// d_out cols: [O0|K1|K2|O2], post combines in place (row-exclusive).
// Fallback (ws < 66 MiB): round-2 segmented path, long-K blocks dispatched
// first to reduce the makespan tail.
// ---------------------------------------------------------------------------

typedef __attribute__((ext_vector_type(8))) short bf16x8_t;
typedef __attribute__((ext_vector_type(4))) float f32x4_t;
typedef __attribute__((ext_vector_type(8))) unsigned short u16x8;

#define NDIM 4096
#define TILE 128
#define BK 32

__device__ __forceinline__ unsigned short f2bf(float f) {
    unsigned int u = __builtin_bit_cast(unsigned int, f);
    u += 0x7fffu + ((u >> 16) & 1u);
    return (unsigned short)(u >> 16);
}

__device__ __forceinline__ void async_copy16(const void* g, void* l) {
    __builtin_amdgcn_global_load_lds(
        (const __attribute__((address_space(1))) void*)g,
        (__attribute__((address_space(3))) void*)l,
        16, 0, 0);
}

// ======================= PRIMARY (Karatsuba) path ==========================

// X (fp32) -> Xp bf16 4096 x 5120: [X0 | Xr | Xi | Xr+Xi | X2]
__global__ __launch_bounds__(256) void fwd_x_k(const float* __restrict__ x,
                                               unsigned short* __restrict__ xp) {
    int gid = blockIdx.x * 256 + threadIdx.x;
    int b   = gid >> 7;
    int j0  = (gid & 127) * 8;
    const float4* src = (const float4*)(x + (size_t)b * NDIM + j0 * 4);
    u16x8 s0, sr, si, ss, s2;
#pragma unroll
    for (int i = 0; i < 8; ++i) {
        float4 v = src[i];
        float r = v.x - v.z, m = v.w - v.y;
        s0[i] = f2bf(v.x + v.y + v.z + v.w);
        sr[i] = f2bf(r);
        si[i] = f2bf(m);
        ss[i] = f2bf(r + m);
        s2[i] = f2bf(v.x - v.y + v.z - v.w);
    }
    unsigned short* dst = xp + (size_t)b * 5120 + j0;
    *(u16x8*)(dst + 0)    = s0;
    *(u16x8*)(dst + 1024) = sr;
    *(u16x8*)(dst + 2048) = si;
    *(u16x8*)(dst + 3072) = ss;
    *(u16x8*)(dst + 4096) = s2;
}

// eigens -> Bp bf16 segments [E0 | Er | Ei-Er | Ei+Er | E2], each 1024x1024
__global__ __launch_bounds__(256) void build_b_k(const float* __restrict__ eig,
                                                 unsigned short* __restrict__ B) {
    int gid = blockIdx.x * 256 + threadIdx.x;
    int y   = gid >> 7;
    int x0  = (gid & 127) * 8;
    const float4* src = (const float4*)(eig + ((size_t)y * 1024 + x0) * 4);
    u16x8 e0, er, ed, es, e2;
#pragma unroll
    for (int i = 0; i < 8; ++i) {
        float4 v = src[i];
        float r = v.x - v.z, m = v.w - v.y;
        e0[i] = f2bf(v.x + v.y + v.z + v.w);
        er[i] = f2bf(r);
        ed[i] = f2bf(m - r);
        es[i] = f2bf(m + r);
        e2[i] = f2bf(v.x - v.y + v.z - v.w);
    }
    size_t p = (size_t)y * 1024 + x0;
    *(u16x8*)(B + 0u       + p) = e0;
    *(u16x8*)(B + 1048576u + p) = er;
    *(u16x8*)(B + 2097152u + p) = ed;
    *(u16x8*)(B + 3145728u + p) = es;
    *(u16x8*)(B + 4194304u + p) = e2;
}

// uniform GEMM: 5 segs x 8 nseg x 32 M-blocks, all K=1024 (32 iters)
__global__ __launch_bounds__(256, 5) void gemm_k(
        const unsigned short* __restrict__ A,   // Xp 4096 x 5120
        const unsigned short* __restrict__ B,   // Bp packed
        float* __restrict__ C,                  // d_out [O0|K1|K2|O2]
        float* __restrict__ K3) {               // ws 4096 x 1024
    __shared__ unsigned short lA[TILE * BK];
    __shared__ unsigned short lB[TILE * BK];

    const int aoffs[5] = {0, 3072, 1024, 2048, 4096};  // X0, Xs, Xr, Xi, X2

    const int seg  = blockIdx.x >> 3;
    const int nseg = blockIdx.x & 7;
    const int blkM = blockIdx.y;

    const int t    = threadIdx.x;
    const int lane = t & 63;
    const int w    = t >> 6;
    const int wm   = (w >> 1) * 64;
    const int wn   = (w & 1) * 64;
    const int lr   = lane & 15;
    const int quad = lane >> 4;

    const int e0 = t * 8;
    const int r0 = e0 >> 5;
    const int c0 = e0 & 31;

    const unsigned short* pa0 = A + (size_t)(blkM * TILE + r0) * 5120 + aoffs[seg] + c0;
    const unsigned short* pa1 = pa0 + (size_t)64 * 5120;
    const unsigned short* pb0 = B + (size_t)seg * 1048576 +
                                (size_t)(nseg * TILE + r0) * 1024 + c0;
    const unsigned short* pb1 = pb0 + (size_t)64 * 1024;

    unsigned short* dA0 = &lA[e0];
    unsigned short* dA1 = &lA[2048 + e0];
    unsigned short* dB0 = &lB[e0];
    unsigned short* dB1 = &lB[2048 + e0];

    const unsigned short* la0 = &lA[(wm + lr) * BK + quad * 8];
    const unsigned short* lb0 = &lB[(wn + lr) * BK + quad * 8];

    f32x4_t acc[4][4] = {};

    for (int k0 = 0; k0 < 1024; k0 += BK) {
        async_copy16(pa0 + k0, dA0);
        async_copy16(pa1 + k0, dA1);
        async_copy16(pb0 + k0, dB0);
        async_copy16(pb1 + k0, dB1);
        asm volatile("s_waitcnt vmcnt(0)" ::: "memory");
        __syncthreads();

        bf16x8_t af[4], bfr[4];
#pragma unroll
        for (int i = 0; i < 4; ++i)
            af[i] = *(const bf16x8_t*)(la0 + i * 16 * BK);
#pragma unroll
        for (int i = 0; i < 4; ++i)
            bfr[i] = *(const bf16x8_t*)(lb0 + i * 16 * BK);

#pragma unroll
        for (int mt = 0; mt < 4; ++mt)
#pragma unroll
            for (int nt = 0; nt < 4; ++nt)
                acc[mt][nt] = __builtin_amdgcn_mfma_f32_16x16x32_bf16(
                    af[mt], bfr[nt], acc[mt][nt], 0, 0, 0);

        __syncthreads();
    }

    // dst: segs {0,1,2}->d_out col regions 0,1,2; seg 3->K3 ws; seg 4->region 3
    float* dstbase;
    int    cstride, colbase;
    if (seg == 3) { dstbase = K3; cstride = 1024; colbase = nseg * TILE; }
    else {
        int regio = (seg < 3) ? seg : 3;
        dstbase = C; cstride = NDIM; colbase = regio * 1024 + nseg * TILE;
    }

    const int orow0 = blkM * TILE + wm + quad * 4;
    const int ocol0 = colbase + wn + lr;
#pragma unroll
    for (int mt = 0; mt < 4; ++mt) {
#pragma unroll
        for (int r = 0; r < 4; ++r) {
            float* dst = dstbase + (size_t)(orow0 + mt * 16 + r) * cstride + ocol0;
#pragma unroll
            for (int nt = 0; nt < 4; ++nt)
                dst[nt * 16] = acc[mt][nt][r];
        }
    }
}

// in-place inverse transform; Or=K1-K3, Oi=K1+K2
__global__ __launch_bounds__(256) void post_k(float* __restrict__ O,
                                              const float* __restrict__ K3) {
    float* row = O + (size_t)blockIdx.x * NDIM;
    const float* k3row = K3 + (size_t)blockIdx.x * 1024;
    const int t = threadIdx.x;
    float v0[4], vr[4], vi[4], v2[4];
#pragma unroll
    for (int i = 0; i < 4; ++i) {
        int y = t + i * 256;
        float k1 = row[1024 + y];
        v0[i] = row[y];
        vr[i] = k1 - k3row[y];
        vi[i] = k1 + row[2048 + y];
        v2[i] = row[3072 + y];
    }
    __syncthreads();
#pragma unroll
    for (int i = 0; i < 4; ++i) {
        int y = t + i * 256;
        float4 o;
        o.x = 0.25f * (v0[i] + 2.0f * vr[i] + v2[i]);
        o.y = 0.25f * (v0[i] - 2.0f * vi[i] - v2[i]);
        o.z = 0.25f * (v0[i] - 2.0f * vr[i] + v2[i]);
        o.w = 0.25f * (v0[i] + 2.0f * vi[i] - v2[i]);
        *(float4*)&row[4 * y] = o;
    }
}

// ======================= FALLBACK (round-2, reordered) =====================

__global__ __launch_bounds__(256) void fwd_x_fb(const float* __restrict__ x,
                                                unsigned short* __restrict__ xp) {
    int gid = blockIdx.x * 256 + threadIdx.x;
    int b   = gid >> 7;
    int j0  = (gid & 127) * 8;
    const float4* src = (const float4*)(x + (size_t)b * NDIM + j0 * 4);
    u16x8 s0, sr, si, s2;
#pragma unroll
    for (int i = 0; i < 8; ++i) {
        float4 v = src[i];
        s0[i] = f2bf(v.x + v.y + v.z + v.w);
        sr[i] = f2bf(v.x - v.z);
        si[i] = f2bf(v.w - v.y);
        s2[i] = f2bf(v.x - v.y + v.z - v.w);
    }
    unsigned short* dst = xp + (size_t)b * NDIM + j0;
    *(u16x8*)(dst + 0)    = s0;
    *(u16x8*)(dst + 1024) = sr;
    *(u16x8*)(dst + 2048) = si;
    *(u16x8*)(dst + 3072) = s2;
}

__global__ __launch_bounds__(256) void build_b_fb(const float* __restrict__ eig,
                                                  unsigned short* __restrict__ B) {
    int gid = blockIdx.x * 256 + threadIdx.x;
    int y   = gid >> 7;
    int x0  = (gid & 127) * 8;
    const float4* src = (const float4*)(eig + ((size_t)y * 1024 + x0) * 4);
    u16x8 e0, er, ei, nei, e2;
#pragma unroll
    for (int i = 0; i < 8; ++i) {
        float4 v = src[i];
        e0[i]  = f2bf(v.x + v.y + v.z + v.w);
        float r = v.x - v.z, s = v.w - v.y;
        er[i]  = f2bf(r);
        ei[i]  = f2bf(s);
        nei[i] = f2bf(-s);
        e2[i]  = f2bf(v.x - v.y + v.z - v.w);
    }
    *(u16x8*)(B + (size_t)y * 1024 + x0) = e0;
    unsigned short* b1r = B + 1048576 + (size_t)y * 2048;
    *(u16x8*)(b1r + x0)        = er;
    *(u16x8*)(b1r + 1024 + x0) = nei;
    unsigned short* b1i = B + 3145728 + (size_t)y * 2048;
    *(u16x8*)(b1i + x0)        = ei;
    *(u16x8*)(b1i + 1024 + x0) = er;
    *(u16x8*)(B + 5242880 + (size_t)y * 1024 + x0) = e2;
}

__global__ __launch_bounds__(256, 2) void gemm_fb(
        const unsigned short* __restrict__ A,
        const unsigned short* __restrict__ B,
        float* __restrict__ C) {
    __shared__ unsigned short lA[TILE * BK];
    __shared__ unsigned short lB[TILE * BK];

    const int Ks[4]   = {1024, 2048, 2048, 1024};
    const int Aoff[4] = {0, 1024, 1024, 3072};
    const size_t Boff[4] = {0u, 1048576u, 3145728u, 5242880u};

    // long-K blocks (segs 1,2) first in dispatch order
    int lin = blockIdx.x;
    int seg, nseg, blkM;
    if (lin < 512) { seg = 1 + ((lin >> 3) & 1); nseg = lin & 7; blkM = lin >> 4; }
    else { int i = lin - 512; seg = ((i >> 3) & 1) * 3; nseg = i & 7; blkM = i >> 4; }

    const int K    = Ks[seg];
    const int aoff = Aoff[seg];
    const unsigned short* Bs = B + Boff[seg];

    const int t    = threadIdx.x;
    const int lane = t & 63;
    const int w    = t >> 6;
    const int wm   = (w >> 1) * 64;
    const int wn   = (w & 1) * 64;
    const int lr   = lane & 15;
    const int quad = lane >> 4;

    const int e0 = t * 8;
    const int r0 = e0 >> 5;
    const int c0 = e0 & 31;

    const unsigned short* pa0 = A + (size_t)(blkM * TILE + r0) * NDIM + aoff + c0;
    const unsigned short* pa1 = pa0 + (size_t)64 * NDIM;
    const unsigned short* pb0 = Bs + (size_t)(nseg * TILE + r0) * K + c0;
    const unsigned short* pb1 = pb0 + (size_t)64 * K;

    unsigned short* dA0 = &lA[e0];
    unsigned short* dA1 = &lA[2048 + e0];
    unsigned short* dB0 = &lB[e0];
    unsigned short* dB1 = &lB[2048 + e0];

    const unsigned short* la0 = &lA[(wm + lr) * BK + quad * 8];
    const unsigned short* lb0 = &lB[(wn + lr) * BK + quad * 8];

    f32x4_t acc[4][4] = {};

    for (int k0 = 0; k0 < K; k0 += BK) {
        async_copy16(pa0 + k0, dA0);
        async_copy16(pa1 + k0, dA1);
        async_copy16(pb0 + k0, dB0);
        async_copy16(pb1 + k0, dB1);
        asm volatile("s_waitcnt vmcnt(0)" ::: "memory");
        __syncthreads();

        bf16x8_t af[4], bfr[4];
#pragma unroll
        for (int i = 0; i < 4; ++i)
            af[i] = *(const bf16x8_t*)(la0 + i * 16 * BK);
#pragma unroll
        for (int i = 0; i < 4; ++i)
            bfr[i] = *(const bf16x8_t*)(lb0 + i * 16 * BK);

#pragma unroll
        for (int mt = 0; mt < 4; ++mt)
#pragma unroll
            for (int nt = 0; nt < 4; ++nt)
                acc[mt][nt] = __builtin_amdgcn_mfma_f32_16x16x32_bf16(
                    af[mt], bfr[nt], acc[mt][nt], 0, 0, 0);

        __syncthreads();
    }

    const int orow0 = blkM * TILE + wm + quad * 4;
    const int ocol0 = seg * 1024 + nseg * TILE + wn + lr;
#pragma unroll
    for (int mt = 0; mt < 4; ++mt) {
#pragma unroll
        for (int r = 0; r < 4; ++r) {
            float* dst = C + (size_t)(orow0 + mt * 16 + r) * NDIM + ocol0;
#pragma unroll
            for (int nt = 0; nt < 4; ++nt)
                dst[nt * 16] = acc[mt][nt][r];
        }
    }
}

__global__ __launch_bounds__(256) void post_fb(float* __restrict__ O) {
    float* row = O + (size_t)blockIdx.x * NDIM;
    const int t = threadIdx.x;
    float v0[4], vr[4], vi[4], v2[4];
#pragma unroll
    for (int i = 0; i < 4; ++i) {
        int y = t + i * 256;
        v0[i] = row[y];
        vr[i] = row[1024 + y];
        vi[i] = row[2048 + y];
        v2[i] = row[3072 + y];
    }
    __syncthreads();
#pragma unroll
    for (int i = 0; i < 4; ++i) {
        int y = t + i * 256;
        float4 o;
        o.x = 0.25f * (v0[i] + 2.0f * vr[i] + v2[i]);
        o.y = 0.25f * (v0[i] - 2.0f * vi[i] - v2[i]);
        o.z = 0.25f * (v0[i] - 2.0f * vr[i] + v2[i]);
        o.w = 0.25f * (v0[i] + 2.0f * vi[i] - v2[i]);
        *(float4*)&row[4 * y] = o;
    }
}

// ============================== launch =====================================

extern "C" void kernel_launch(void* const* d_in, const int* in_sizes, int n_in,
                              void* d_out, int out_size, void* d_ws, size_t ws_size,
                              hipStream_t stream) {
    const float* x   = (const float*)d_in[0];
    const float* eig = (const float*)d_in[1];
    float* out = (float*)d_out;

    const size_t NEED = (size_t)(40 + 10 + 16) * 1024 * 1024;  // 66 MiB

    if (ws_size >= NEED) {
        unsigned short* Xp = (unsigned short*)d_ws;                          // 40 MiB
        unsigned short* Bp = (unsigned short*)((char*)d_ws + 41943040u);     // 10 MiB
        float*          K3 = (float*)((char*)d_ws + 52428800u);             // 16 MiB

        fwd_x_k<<<(NDIM * 128) / 256, 256, 0, stream>>>(x, Xp);
        build_b_k<<<(1024 * 128) / 256, 256, 0, stream>>>(eig, Bp);
        dim3 grid(40, NDIM / TILE);                    // 5 segs x 8 nseg, 32 M
        gemm_k<<<grid, 256, 0, stream>>>(Xp, Bp, out, K3);
        post_k<<<NDIM, 256, 0, stream>>>(out, K3);
    } else {
        unsigned short* Xp = (unsigned short*)d_ws;
        unsigned short* Bp = Xp + (size_t)NDIM * NDIM;

        fwd_x_fb<<<(NDIM * 128) / 256, 256, 0, stream>>>(x, Xp);
        build_b_fb<<<(1024 * 128) / 256, 256, 0, stream>>>(eig, Bp);
        gemm_fb<<<dim3(1024, 1), 256, 0, stream>>>(Xp, Bp, out);
        post_fb<<<NDIM, 256, 0, stream>>>(out);
    }
}

// Round 4
// 212.740 us; speedup vs baseline: 1.0852x; 1.0852x over previous
//
#include <hip/hip_runtime.h>

// ---------------------------------------------------------------------------
// CirculantLinear via length-4 rfft + 3-mult complex product (Karatsuba):
//   K1=(Xr+Xi)·Er, K2=Xr·(Ei-Er), K3=Xi·(Ei+Er);  Or=K1-K3, Oi=K1+K2
// 5 uniform bf16 GEMMs (M=4096, N=1024, K=1024 each; 42.9 GFLOP total),
// 1280 identical blocks, XCD-swizzled so the 8 N-blocks sharing an A slab
// land on one XCD (L2 locality).
//
// ws: [0,40MiB) Xp bf16 4096x5120 [X0|Xr|Xi|Xr+Xi|X2]
//     [40,50MiB) Bp bf16 5x(1024x1024) [E0|Er|Ei-Er|Ei+Er|E2]
//     [50,66MiB) K3 fp32 4096x1024
// d_out cols [O0|K1|K2|O2] fp32, post combines in place (row-exclusive).
// ---------------------------------------------------------------------------

typedef __attribute__((ext_vector_type(8))) short bf16x8_t;
typedef __attribute__((ext_vector_type(4))) float f32x4_t;
typedef __attribute__((ext_vector_type(8))) unsigned short u16x8;

#define NDIM 4096
#define TILE 128
#define BK 32

__device__ __forceinline__ unsigned short f2bf(float f) {
    unsigned int u = __builtin_bit_cast(unsigned int, f);
    u += 0x7fffu + ((u >> 16) & 1u);
    return (unsigned short)(u >> 16);
}

__device__ __forceinline__ void async_copy16(const void* g, void* l) {
    __builtin_amdgcn_global_load_lds(
        (const __attribute__((address_space(1))) void*)g,
        (__attribute__((address_space(3))) void*)l,
        16, 0, 0);
}

// ======================= PRIMARY (Karatsuba) path ==========================

// fused pre-pass: one float4 (one mini-block) per thread, fully coalesced.
// blocks [0,16384): X -> Xp ; blocks [16384,20480): eigens -> Bp
__global__ __launch_bounds__(256) void pre_k(const float* __restrict__ x,
                                             const float* __restrict__ eig,
                                             unsigned short* __restrict__ xp,
                                             unsigned short* __restrict__ B) {
    if (blockIdx.x < 16384) {
        int gid = blockIdx.x * 256 + threadIdx.x;     // 0 .. 4096*1024-1
        int b = gid >> 10, j = gid & 1023;
        float4 v = ((const float4*)x)[(size_t)b * 1024 + j];
        float r = v.x - v.z, m = v.w - v.y;
        unsigned short* dst = xp + (size_t)b * 5120 + j;
        dst[0]    = f2bf(v.x + v.y + v.z + v.w);
        dst[1024] = f2bf(r);
        dst[2048] = f2bf(m);
        dst[3072] = f2bf(r + m);
        dst[4096] = f2bf(v.x - v.y + v.z - v.w);
    } else {
        int gid = (blockIdx.x - 16384) * 256 + threadIdx.x;  // 0 .. 1024*1024-1
        int y = gid >> 10, c = gid & 1023;
        float4 v = ((const float4*)eig)[(size_t)y * 1024 + c];
        float r = v.x - v.z, m = v.w - v.y;
        size_t p = (size_t)y * 1024 + c;
        B[p]            = f2bf(v.x + v.y + v.z + v.w);
        B[p + 1048576u] = f2bf(r);
        B[p + 2097152u] = f2bf(m - r);
        B[p + 3145728u] = f2bf(m + r);
        B[p + 4194304u] = f2bf(v.x - v.y + v.z - v.w);
    }
}

// uniform GEMM, 1280 blocks, XCD-swizzled decomposition of blockIdx.x.
__global__ __launch_bounds__(256, 5) void gemm_k(
        const unsigned short* __restrict__ A,   // Xp 4096 x 5120
        const unsigned short* __restrict__ B,   // Bp packed
        float* __restrict__ C,                  // d_out [O0|K1|K2|O2]
        float* __restrict__ K3) {               // ws 4096 x 1024
    __shared__ unsigned short lA[TILE * BK];
    __shared__ unsigned short lB[TILE * BK];

    const int aoffs[5] = {0, 3072, 1024, 2048, 4096};  // X0, Xs, Xr, Xi, X2

    // swizzle: all 8 nsegs of one (seg,blkM) pair share raw%8 (same XCD)
    const int raw       = blockIdx.x;        // [0,1280)
    const int r_xcd     = raw & 7;
    const int local     = raw >> 3;          // [0,160)
    const int nseg      = local & 7;
    const int pairLocal = local >> 3;        // [0,20)
    const int p         = r_xcd * 20 + pairLocal;  // [0,160)
    const int seg       = p >> 5;            // [0,5)
    const int blkM      = p & 31;            // [0,32)

    const int t    = threadIdx.x;
    const int lane = t & 63;
    const int w    = t >> 6;
    const int wm   = (w >> 1) * 64;
    const int wn   = (w & 1) * 64;
    const int lr   = lane & 15;
    const int quad = lane >> 4;

    const int e0 = t * 8;
    const int r0 = e0 >> 5;
    const int c0 = e0 & 31;

    const unsigned short* pa0 = A + (size_t)(blkM * TILE + r0) * 5120 + aoffs[seg] + c0;
    const unsigned short* pa1 = pa0 + (size_t)64 * 5120;
    const unsigned short* pb0 = B + (size_t)seg * 1048576 +
                                (size_t)(nseg * TILE + r0) * 1024 + c0;
    const unsigned short* pb1 = pb0 + (size_t)64 * 1024;

    unsigned short* dA0 = &lA[e0];
    unsigned short* dA1 = &lA[2048 + e0];
    unsigned short* dB0 = &lB[e0];
    unsigned short* dB1 = &lB[2048 + e0];

    const unsigned short* la0 = &lA[(wm + lr) * BK + quad * 8];
    const unsigned short* lb0 = &lB[(wn + lr) * BK + quad * 8];

    f32x4_t acc[4][4] = {};

    for (int k0 = 0; k0 < 1024; k0 += BK) {
        async_copy16(pa0 + k0, dA0);
        async_copy16(pa1 + k0, dA1);
        async_copy16(pb0 + k0, dB0);
        async_copy16(pb1 + k0, dB1);
        asm volatile("s_waitcnt vmcnt(0)" ::: "memory");
        __syncthreads();

        bf16x8_t af[4], bfr[4];
#pragma unroll
        for (int i = 0; i < 4; ++i)
            af[i] = *(const bf16x8_t*)(la0 + i * 16 * BK);
#pragma unroll
        for (int i = 0; i < 4; ++i)
            bfr[i] = *(const bf16x8_t*)(lb0 + i * 16 * BK);

#pragma unroll
        for (int mt = 0; mt < 4; ++mt)
#pragma unroll
            for (int nt = 0; nt < 4; ++nt)
                acc[mt][nt] = __builtin_amdgcn_mfma_f32_16x16x32_bf16(
                    af[mt], bfr[nt], acc[mt][nt], 0, 0, 0);

        __syncthreads();
    }

    float* dstbase;
    int    cstride, colbase;
    if (seg == 3) { dstbase = K3; cstride = 1024; colbase = nseg * TILE; }
    else {
        int regio = (seg < 3) ? seg : 3;
        dstbase = C; cstride = NDIM; colbase = regio * 1024 + nseg * TILE;
    }

    const int orow0 = blkM * TILE + wm + quad * 4;
    const int ocol0 = colbase + wn + lr;
#pragma unroll
    for (int mt = 0; mt < 4; ++mt) {
#pragma unroll
        for (int r = 0; r < 4; ++r) {
            float* dst = dstbase + (size_t)(orow0 + mt * 16 + r) * cstride + ocol0;
#pragma unroll
            for (int nt = 0; nt < 4; ++nt)
                dst[nt * 16] = acc[mt][nt][r];
        }
    }
}

// in-place inverse transform, fully vectorized. One block per row.
__global__ __launch_bounds__(256) void post_k(float* __restrict__ O,
                                              const float* __restrict__ K3) {
    float* row = O + (size_t)blockIdx.x * NDIM;
    const float* k3row = K3 + (size_t)blockIdx.x * 1024;
    const int t = threadIdx.x;

    float4 v0 = *(const float4*)(row + 4 * t);
    float4 k1 = *(const float4*)(row + 1024 + 4 * t);
    float4 k2 = *(const float4*)(row + 2048 + 4 * t);
    float4 v2 = *(const float4*)(row + 3072 + 4 * t);
    float4 k3 = *(const float4*)(k3row + 4 * t);
    __syncthreads();

    const float* a0 = (const float*)&v0;
    const float* a1 = (const float*)&k1;
    const float* a2 = (const float*)&k2;
    const float* a3 = (const float*)&v2;
    const float* a4 = (const float*)&k3;
#pragma unroll
    for (int i = 0; i < 4; ++i) {
        float vr = a1[i] - a4[i];          // Or = K1 - K3
        float vi = a1[i] + a2[i];          // Oi = K1 + K2
        float4 o;
        o.x = 0.25f * (a0[i] + 2.0f * vr + a3[i]);
        o.y = 0.25f * (a0[i] - 2.0f * vi - a3[i]);
        o.z = 0.25f * (a0[i] - 2.0f * vr + a3[i]);
        o.w = 0.25f * (a0[i] + 2.0f * vi - a3[i]);
        *(float4*)(row + 16 * t + 4 * i) = o;
    }
}

// ======================= FALLBACK (round-2 path) ===========================

__global__ __launch_bounds__(256) void fwd_x_fb(const float* __restrict__ x,
                                                unsigned short* __restrict__ xp) {
    int gid = blockIdx.x * 256 + threadIdx.x;
    int b = gid >> 10, j = gid & 1023;
    float4 v = ((const float4*)x)[(size_t)b * 1024 + j];
    unsigned short* dst = xp + (size_t)b * NDIM + j;
    dst[0]    = f2bf(v.x + v.y + v.z + v.w);
    dst[1024] = f2bf(v.x - v.z);
    dst[2048] = f2bf(v.w - v.y);
    dst[3072] = f2bf(v.x - v.y + v.z - v.w);
}

__global__ __launch_bounds__(256) void build_b_fb(const float* __restrict__ eig,
                                                  unsigned short* __restrict__ B) {
    int gid = blockIdx.x * 256 + threadIdx.x;
    int y = gid >> 10, c = gid & 1023;
    float4 v = ((const float4*)eig)[(size_t)y * 1024 + c];
    float r = v.x - v.z, s = v.w - v.y;
    B[(size_t)y * 1024 + c] = f2bf(v.x + v.y + v.z + v.w);
    unsigned short* b1r = B + 1048576 + (size_t)y * 2048;
    b1r[c]        = f2bf(r);
    b1r[1024 + c] = f2bf(-s);
    unsigned short* b1i = B + 3145728 + (size_t)y * 2048;
    b1i[c]        = f2bf(s);
    b1i[1024 + c] = f2bf(r);
    B[5242880 + (size_t)y * 1024 + c] = f2bf(v.x - v.y + v.z - v.w);
}

__global__ __launch_bounds__(256, 2) void gemm_fb(
        const unsigned short* __restrict__ A,
        const unsigned short* __restrict__ B,
        float* __restrict__ C) {
    __shared__ unsigned short lA[TILE * BK];
    __shared__ unsigned short lB[TILE * BK];

    const int Ks[4]   = {1024, 2048, 2048, 1024};
    const int Aoff[4] = {0, 1024, 1024, 3072};
    const size_t Boff[4] = {0u, 1048576u, 3145728u, 5242880u};

    int lin = blockIdx.x;
    int seg, nseg, blkM;
    if (lin < 512) { seg = 1 + ((lin >> 3) & 1); nseg = lin & 7; blkM = lin >> 4; }
    else { int i = lin - 512; seg = ((i >> 3) & 1) * 3; nseg = i & 7; blkM = i >> 4; }

    const int K    = Ks[seg];
    const int aoff = Aoff[seg];
    const unsigned short* Bs = B + Boff[seg];

    const int t    = threadIdx.x;
    const int lane = t & 63;
    const int w    = t >> 6;
    const int wm   = (w >> 1) * 64;
    const int wn   = (w & 1) * 64;
    const int lr   = lane & 15;
    const int quad = lane >> 4;

    const int e0 = t * 8;
    const int r0 = e0 >> 5;
    const int c0 = e0 & 31;

    const unsigned short* pa0 = A + (size_t)(blkM * TILE + r0) * NDIM + aoff + c0;
    const unsigned short* pa1 = pa0 + (size_t)64 * NDIM;
    const unsigned short* pb0 = Bs + (size_t)(nseg * TILE + r0) * K + c0;
    const unsigned short* pb1 = pb0 + (size_t)64 * K;

    unsigned short* dA0 = &lA[e0];
    unsigned short* dA1 = &lA[2048 + e0];
    unsigned short* dB0 = &lB[e0];
    unsigned short* dB1 = &lB[2048 + e0];

    const unsigned short* la0 = &lA[(wm + lr) * BK + quad * 8];
    const unsigned short* lb0 = &lB[(wn + lr) * BK + quad * 8];

    f32x4_t acc[4][4] = {};

    for (int k0 = 0; k0 < K; k0 += BK) {
        async_copy16(pa0 + k0, dA0);
        async_copy16(pa1 + k0, dA1);
        async_copy16(pb0 + k0, dB0);
        async_copy16(pb1 + k0, dB1);
        asm volatile("s_waitcnt vmcnt(0)" ::: "memory");
        __syncthreads();

        bf16x8_t af[4], bfr[4];
#pragma unroll
        for (int i = 0; i < 4; ++i)
            af[i] = *(const bf16x8_t*)(la0 + i * 16 * BK);
#pragma unroll
        for (int i = 0; i < 4; ++i)
            bfr[i] = *(const bf16x8_t*)(lb0 + i * 16 * BK);

#pragma unroll
        for (int mt = 0; mt < 4; ++mt)
#pragma unroll
            for (int nt = 0; nt < 4; ++nt)
                acc[mt][nt] = __builtin_amdgcn_mfma_f32_16x16x32_bf16(
                    af[mt], bfr[nt], acc[mt][nt], 0, 0, 0);

        __syncthreads();
    }

    const int orow0 = blkM * TILE + wm + quad * 4;
    const int ocol0 = seg * 1024 + nseg * TILE + wn + lr;
#pragma unroll
    for (int mt = 0; mt < 4; ++mt) {
#pragma unroll
        for (int r = 0; r < 4; ++r) {
            float* dst = C + (size_t)(orow0 + mt * 16 + r) * NDIM + ocol0;
#pragma unroll
            for (int nt = 0; nt < 4; ++nt)
                dst[nt * 16] = acc[mt][nt][r];
        }
    }
}

__global__ __launch_bounds__(256) void post_fb(float* __restrict__ O) {
    float* row = O + (size_t)blockIdx.x * NDIM;
    const int t = threadIdx.x;
    float4 v0 = *(const float4*)(row + 4 * t);
    float4 vr = *(const float4*)(row + 1024 + 4 * t);
    float4 vi = *(const float4*)(row + 2048 + 4 * t);
    float4 v2 = *(const float4*)(row + 3072 + 4 * t);
    __syncthreads();
    const float* a0 = (const float*)&v0;
    const float* ar = (const float*)&vr;
    const float* ai = (const float*)&vi;
    const float* a2 = (const float*)&v2;
#pragma unroll
    for (int i = 0; i < 4; ++i) {
        float4 o;
        o.x = 0.25f * (a0[i] + 2.0f * ar[i] + a2[i]);
        o.y = 0.25f * (a0[i] - 2.0f * ai[i] - a2[i]);
        o.z = 0.25f * (a0[i] - 2.0f * ar[i] + a2[i]);
        o.w = 0.25f * (a0[i] + 2.0f * ai[i] - a2[i]);
        *(float4*)(row + 16 * t + 4 * i) = o;
    }
}

// ============================== launch =====================================

extern "C" void kernel_launch(void* const* d_in, const int* in_sizes, int n_in,
                              void* d_out, int out_size, void* d_ws, size_t ws_size,
                              hipStream_t stream) {
    const float* x   = (const float*)d_in[0];
    const float* eig = (const float*)d_in[1];
    float* out = (float*)d_out;

    const size_t NEED = (size_t)66 * 1024 * 1024;

    if (ws_size >= NEED) {
        unsigned short* Xp = (unsigned short*)d_ws;                      // 40 MiB
        unsigned short* Bp = (unsigned short*)((char*)d_ws + 41943040u); // 10 MiB
        float*          K3 = (float*)((char*)d_ws + 52428800u);         // 16 MiB

        pre_k<<<16384 + 4096, 256, 0, stream>>>(x, eig, Xp, Bp);
        gemm_k<<<1280, 256, 0, stream>>>(Xp, Bp, out, K3);
        post_k<<<NDIM, 256, 0, stream>>>(out, K3);
    } else {
        unsigned short* Xp = (unsigned short*)d_ws;
        unsigned short* Bp = Xp + (size_t)NDIM * NDIM;

        fwd_x_fb<<<(NDIM * 1024) / 256, 256, 0, stream>>>(x, Xp);
        build_b_fb<<<(1024 * 1024) / 256, 256, 0, stream>>>(eig, Bp);
        gemm_fb<<<dim3(1024, 1), 256, 0, stream>>>(Xp, Bp, out);
        post_fb<<<NDIM, 256, 0, stream>>>(out);
    }
}